// Round 4
// baseline (384.633 us; speedup 1.0000x reference)
//
#include <hip/hip_runtime.h>

#define SEQ 512
#define BATCH 8192
#define HDIM 10
#define LOG2E 1.44269504088896340736f

__device__ __forceinline__ float bperm(int addr_bytes, float v) {
    return __int_as_float(__builtin_amdgcn_ds_bpermute(addr_bytes, __float_as_int(v)));
}
__device__ __forceinline__ float fexp2(float x) { return __builtin_amdgcn_exp2f(x); }
__device__ __forceinline__ float frcp(float x)  { return __builtin_amdgcn_rcpf(x); }

// Row-split LSTM: 16 lanes per batch element; the 80 gate-rows of one
// pipelined step (40 L0 rows for t+1, 40 L1 rows for t) are spread over all
// 16 lanes as 6 uniform-width slots (3x12-wide L0, 3x20-wide L1).
// Slot s row id: p = s*16 + lane16 (p<40 valid; rest dummy with zero weights).
// Activation sigma/tanh folded to r = rcp(1+exp2(z~)) with per-row prescale
// baked into weights and per-row (a,b) post: act = a*r + b.
//
// Gate transpose back to unit-owner lanes: ONE full-exec ds_bpermute per
// gate. Where a gate's rows straddle two slots, the SOURCE register is
// pre-merged with a full-exec select (v_cndmask) BEFORE the bpermute.
// NEVER put a bpermute inside a divergent ternary: ds_bpermute applies EXEC
// to the source read (inactive source lane -> 0) — that was round 3's bug.
__global__ __launch_bounds__(256, 2) void lstm2_fc_kernel(
    const float* __restrict__ x,
    const float* __restrict__ w_ih0, const float* __restrict__ w_hh0,
    const float* __restrict__ b_ih0, const float* __restrict__ b_hh0,
    const float* __restrict__ w_ih1, const float* __restrict__ w_hh1,
    const float* __restrict__ b_ih1, const float* __restrict__ b_hh1,
    const float* __restrict__ fc_w, const float* __restrict__ fc_b,
    float* __restrict__ out)
{
    const int tid    = threadIdx.x;
    const int lane16 = tid & 15;
    const int b      = blockIdx.x * 16 + (tid >> 4);
    const int gbase  = (tid & 63) & 48;      // 16-lane group base within wave

    // ---- per-slot weights (prescaled), biases, post-scale (a,b) ----
    float w0x[3][2], w0h[3][HDIM], bias0[3];
    float w1a[3][HDIM], w1b[3][HDIM], bias1[3];
    float pa[3], pb[3];
    #pragma unroll
    for (int s = 0; s < 3; ++s) {
        const int  pp    = s * 16 + lane16;
        const bool valid = (pp < 40);
        const int  r     = valid ? pp : 0;
        const int  tau   = r / 10;                   // 0=i,1=f,2=g,3=o
        const float sc   = (tau == 2) ? (2.0f * LOG2E) : (-LOG2E);
        pa[s] = (tau == 2) ? -2.0f : 1.0f;
        pb[s] = (tau == 2) ?  1.0f : 0.0f;
        const float m = valid ? sc : 0.0f;
        w0x[s][0] = m * w_ih0[r * 2 + 0];
        w0x[s][1] = m * w_ih0[r * 2 + 1];
        bias0[s]  = m * (b_ih0[r] + b_hh0[r]);
        bias1[s]  = m * (b_ih1[r] + b_hh1[r]);
        #pragma unroll
        for (int j = 0; j < HDIM; ++j) {
            w0h[s][j] = m * w_hh0[r * HDIM + j];
            w1a[s][j] = m * w_ih1[r * HDIM + j];
            w1b[s][j] = m * w_hh1[r * HDIM + j];
        }
    }

    // ---- gather addresses (unit-owner side), hoisted ----
    const int u  = (lane16 < HDIM) ? lane16 : 9;     // clamp dummies
    const int ai = (gbase + u) * 4;                                  // row u     (slot0, act0)
    const int af = (gbase + ((u < 6) ? (10 + u) : (u - 6))) * 4;     // row 10+u  (slot0/1)
    const int ag = (gbase + 4 + u) * 4;                              // row 20+u  (slot1, act1)
    const int ao = (gbase + ((u < 2) ? (14 + u) : (u - 2))) * 4;     // row 30+u  (slot1/2)
    const bool src_f = (lane16 < 4);   // source-side: lanes 0..3 serve f rows 16..19 (slot1)
    const bool src_o = (lane16 < 8);   // source-side: lanes 0..7 serve o rows 32..39 (slot2)

    // ---- h-broadcast addresses, hoisted ----
    int hb[HDIM];
    #pragma unroll
    for (int j = 0; j < HDIM; ++j) hb[j] = (gbase + j) * 4;

    // ---- state ----
    float h1[HDIM], h2[HDIM];
    #pragma unroll
    for (int j = 0; j < HDIM; ++j) { h1[j] = 0.0f; h2[j] = 0.0f; }
    float c1 = 0.0f, c2 = 0.0f;

    // ---- prologue: L0 at t=0 (h1 = 0) ----
    {
        const float2 x0 = *reinterpret_cast<const float2*>(x + (size_t)b * 2);
        float z0[3];
        #pragma unroll
        for (int s = 0; s < 3; ++s)
            z0[s] = bias0[s] + w0x[s][0] * x0.x + w0x[s][1] * x0.y;
        const float d0 = 1.0f + fexp2(z0[0]);
        const float d1 = 1.0f + fexp2(z0[1]);
        const float d2 = 1.0f + fexp2(z0[2]);
        const float ip01 = frcp(d0 * d1);
        const float act0 = fmaf(pa[0], d1 * ip01, pb[0]);
        const float act1 = fmaf(pa[1], d0 * ip01, pb[1]);
        const float act2 = fmaf(pa[2], frcp(d2), pb[2]);
        const float fsrc = src_f ? act1 : act0;
        const float osrc = src_o ? act2 : act1;
        const float iA = bperm(ai, act0);
        const float fA = bperm(af, fsrc);
        const float gA = bperm(ag, act1);
        const float oA = bperm(ao, osrc);
        c1 = iA * gA;                                  // c was 0
        const float e1 = 1.0f + fexp2(2.0f * LOG2E * c1);
        const float th1 = fmaf(-2.0f, frcp(e1), 1.0f);
        const float h1o = oA * th1;
        (void)fA;
        #pragma unroll
        for (int j = 0; j < HDIM; ++j) h1[j] = bperm(hb[j], h1o);
    }

    float2 xv = *reinterpret_cast<const float2*>(x + ((size_t)1 * BATCH + b) * 2);

    // ---- main loop: iter t computes L0[t+1] and L1[t] ----
    for (int t = 0; t < SEQ - 1; ++t) {
        const int tn = (t + 2 < SEQ) ? (t + 2) : (SEQ - 1);
        const float2 xnext =
            *reinterpret_cast<const float2*>(x + ((size_t)tn * BATCH + b) * 2);

        // -- 6 slot dots --
        float z0[3], z1[3];
        #pragma unroll
        for (int s = 0; s < 3; ++s) {
            float acc = bias0[s] + w0x[s][0] * xv.x + w0x[s][1] * xv.y;
            #pragma unroll
            for (int j = 0; j < HDIM; ++j) acc = fmaf(w0h[s][j], h1[j], acc);
            z0[s] = acc;
        }
        #pragma unroll
        for (int s = 0; s < 3; ++s) {
            float acc = bias1[s];
            #pragma unroll
            for (int j = 0; j < HDIM; ++j) acc = fmaf(w1a[s][j], h1[j], acc);
            #pragma unroll
            for (int j = 0; j < HDIM; ++j) acc = fmaf(w1b[s][j], h2[j], acc);
            z1[s] = acc;
        }

        // -- activations (paired rcp) --
        const float d0 = 1.0f + fexp2(z0[0]);
        const float d1 = 1.0f + fexp2(z0[1]);
        const float d2 = 1.0f + fexp2(z0[2]);
        const float d3 = 1.0f + fexp2(z1[0]);
        const float d4 = 1.0f + fexp2(z1[1]);
        const float d5 = 1.0f + fexp2(z1[2]);
        const float ip01 = frcp(d0 * d1);
        const float ip23 = frcp(d2 * d3);
        const float ip45 = frcp(d4 * d5);
        const float act0 = fmaf(pa[0], d1 * ip01, pb[0]);
        const float act1 = fmaf(pa[1], d0 * ip01, pb[1]);
        const float act2 = fmaf(pa[2], d3 * ip23, pb[2]);
        const float act3 = fmaf(pa[0], d2 * ip23, pb[0]);
        const float act4 = fmaf(pa[1], d5 * ip45, pb[1]);
        const float act5 = fmaf(pa[2], d4 * ip45, pb[2]);

        // -- merge straddling-gate sources (full-exec cndmask), then 8 bperms --
        const float fsrcA = src_f ? act1 : act0;
        const float osrcA = src_o ? act2 : act1;
        const float fsrcB = src_f ? act4 : act3;
        const float osrcB = src_o ? act5 : act4;

        const float iA = bperm(ai, act0);
        const float fA = bperm(af, fsrcA);
        const float gA = bperm(ag, act1);
        const float oA = bperm(ao, osrcA);
        const float iB = bperm(ai, act3);
        const float fB = bperm(af, fsrcB);
        const float gB = bperm(ag, act4);
        const float oB = bperm(ao, osrcB);

        // -- c/h updates (paired rcp for the two tanh(c)) --
        c1 = fmaf(fA, c1, iA * gA);
        c2 = fmaf(fB, c2, iB * gB);
        const float e1 = 1.0f + fexp2(2.0f * LOG2E * c1);
        const float e2 = 1.0f + fexp2(2.0f * LOG2E * c2);
        const float ipc = frcp(e1 * e2);
        const float th1 = fmaf(-2.0f, e2 * ipc, 1.0f);
        const float th2 = fmaf(-2.0f, e1 * ipc, 1.0f);
        const float h1o = oA * th1;
        const float h2o = oB * th2;

        // -- broadcast h to all 16 lanes of the group --
        #pragma unroll
        for (int j = 0; j < HDIM; ++j) h1[j] = bperm(hb[j], h1o);
        #pragma unroll
        for (int j = 0; j < HDIM; ++j) h2[j] = bperm(hb[j], h2o);

        xv = xnext;
    }

    // ---- epilogue: L1 at t = SEQ-1 ----
    {
        float z1[3];
        #pragma unroll
        for (int s = 0; s < 3; ++s) {
            float acc = bias1[s];
            #pragma unroll
            for (int j = 0; j < HDIM; ++j) acc = fmaf(w1a[s][j], h1[j], acc);
            #pragma unroll
            for (int j = 0; j < HDIM; ++j) acc = fmaf(w1b[s][j], h2[j], acc);
            z1[s] = acc;
        }
        const float d3 = 1.0f + fexp2(z1[0]);
        const float d4 = 1.0f + fexp2(z1[1]);
        const float d5 = 1.0f + fexp2(z1[2]);
        const float ip34 = frcp(d3 * d4);
        const float act3 = fmaf(pa[0], d4 * ip34, pb[0]);
        const float act4 = fmaf(pa[1], d3 * ip34, pb[1]);
        const float act5 = fmaf(pa[2], frcp(d5), pb[2]);
        const float fsrcB = src_f ? act4 : act3;
        const float osrcB = src_o ? act5 : act4;
        const float iB = bperm(ai, act3);
        const float fB = bperm(af, fsrcB);
        const float gB = bperm(ag, act4);
        const float oB = bperm(ao, osrcB);
        c2 = fmaf(fB, c2, iB * gB);
        const float e2 = 1.0f + fexp2(2.0f * LOG2E * c2);
        const float th2 = fmaf(-2.0f, frcp(e2), 1.0f);
        const float h2o = oB * th2;
        #pragma unroll
        for (int j = 0; j < HDIM; ++j) h2[j] = bperm(hb[j], h2o);
    }

    // ---- FC ----
    if (lane16 < 2) {
        float acc = fc_b[lane16];
        #pragma unroll
        for (int j = 0; j < HDIM; ++j) acc = fmaf(fc_w[lane16 * HDIM + j], h2[j], acc);
        out[(size_t)b * 2 + lane16] = acc;
    }
}

extern "C" void kernel_launch(void* const* d_in, const int* in_sizes, int n_in,
                              void* d_out, int out_size, void* d_ws, size_t ws_size,
                              hipStream_t stream) {
    const float* x     = (const float*)d_in[0];
    const float* w_ih0 = (const float*)d_in[1];
    const float* w_hh0 = (const float*)d_in[2];
    const float* b_ih0 = (const float*)d_in[3];
    const float* b_hh0 = (const float*)d_in[4];
    const float* w_ih1 = (const float*)d_in[5];
    const float* w_hh1 = (const float*)d_in[6];
    const float* b_ih1 = (const float*)d_in[7];
    const float* b_hh1 = (const float*)d_in[8];
    const float* fc_w  = (const float*)d_in[9];
    const float* fc_b  = (const float*)d_in[10];
    float* out = (float*)d_out;

    const int threads = 256;                  // 16 batch elements per block
    const int blocks  = BATCH / 16;           // 512 blocks -> 2 blocks/CU
    lstm2_fc_kernel<<<blocks, threads, 0, stream>>>(
        x, w_ih0, w_hh0, b_ih0, b_hh0,
        w_ih1, w_hh1, b_ih1, b_hh1, fc_w, fc_b, out);
}

// Round 5
// 308.911 us; speedup vs baseline: 1.2451x; 1.2451x over previous
//
#include <hip/hip_runtime.h>

#define SEQ 512
#define BATCH 8192
#define HDIM 10
#define LOG2E  1.44269504088896340736f
#define LOG2E2 2.88539008177792681472f   // 2*log2(e)

typedef float f2 __attribute__((ext_vector_type(2)));

__device__ __forceinline__ float bperm(int addr_bytes, float v) {
    return __int_as_float(__builtin_amdgcn_ds_bpermute(addr_bytes, __float_as_int(v)));
}
__device__ __forceinline__ float fexp2(float x) { return __builtin_amdgcn_exp2f(x); }
__device__ __forceinline__ float frcp(float x)  { return __builtin_amdgcn_rcpf(x); }
__device__ __forceinline__ f2 mk2(float a, float b) { f2 r; r.x = a; r.y = b; return r; }
__device__ __forceinline__ f2 fma2(f2 a, f2 b, f2 c) { return __builtin_elementwise_fma(a, b, c); }

// Pin a value into VGPRs: the loop then uses the asm output, which the
// compiler cannot rematerialize by re-loading from global memory in-loop.
// (Rounds 1/2/4 had VGPR_Count < weight-float count -> hidden in-loop
// global reloads every timestep; this forces true register residency.)
#define PIN(v)  asm volatile("" : "+v"(v))

// Unit-per-lane LSTM (round-2 structure): 16 lanes per batch element, lane
// u in [0,10) owns hidden unit u and computes its 4 gate rows for both
// layers; c is lane-local; h broadcast via ds_bpermute (10 per layer).
// Software pipeline: iteration t computes L0[t+1] then L1[t], so each
// broadcast has ~60+ instructions before its first consumer.
// Dot products use packed fp32 (v_pk_fma_f32) on float2-packed weights.
// Activations: sigma/tanh folded to rcp(1+exp2(z~)) with prescale baked
// into weights; i/f and g/o share one reciprocal each (rcp(a*b) trick).
__global__ __launch_bounds__(256, 2) void lstm2_fc_kernel(
    const float* __restrict__ x,
    const float* __restrict__ w_ih0, const float* __restrict__ w_hh0,
    const float* __restrict__ b_ih0, const float* __restrict__ b_hh0,
    const float* __restrict__ w_ih1, const float* __restrict__ w_hh1,
    const float* __restrict__ b_ih1, const float* __restrict__ b_hh1,
    const float* __restrict__ fc_w, const float* __restrict__ fc_b,
    float* __restrict__ out)
{
    const int tid    = threadIdx.x;
    const int lane16 = tid & 15;
    const int b      = blockIdx.x * 16 + (tid >> 4);
    const int gbase  = tid & 48;                 // 16-lane group base in wave
    const int u      = (lane16 < HDIM) ? lane16 : 9;   // clamp dummy lanes

    // ---- load loop-invariant weights, packed + prescaled ----
    f2 wi0p[4], wh0p[4][5], wi1p[4][5], wh1p[4][5];
    float bb0[4], bb1[4];
    #pragma unroll
    for (int g = 0; g < 4; ++g) {
        const int r   = g * 10 + u;
        const float m = (g == 2) ? LOG2E2 : -LOG2E;
        wi0p[g] = mk2(m * w_ih0[r * 2 + 0], m * w_ih0[r * 2 + 1]);
        bb0[g]  = m * (b_ih0[r] + b_hh0[r]);
        bb1[g]  = m * (b_ih1[r] + b_hh1[r]);
        #pragma unroll
        for (int k = 0; k < 5; ++k) {
            wh0p[g][k] = mk2(m * w_hh0[r * HDIM + 2 * k], m * w_hh0[r * HDIM + 2 * k + 1]);
            wi1p[g][k] = mk2(m * w_ih1[r * HDIM + 2 * k], m * w_ih1[r * HDIM + 2 * k + 1]);
            wh1p[g][k] = mk2(m * w_hh1[r * HDIM + 2 * k], m * w_hh1[r * HDIM + 2 * k + 1]);
        }
    }
    // force true VGPR residency for everything used in the hot loop
    #pragma unroll
    for (int g = 0; g < 4; ++g) {
        PIN(wi0p[g]); PIN(bb0[g]); PIN(bb1[g]);
        #pragma unroll
        for (int k = 0; k < 5; ++k) { PIN(wh0p[g][k]); PIN(wi1p[g][k]); PIN(wh1p[g][k]); }
    }

    // ---- h-broadcast addresses ----
    int hb[HDIM];
    #pragma unroll
    for (int j = 0; j < HDIM; ++j) hb[j] = (gbase + j) * 4;

    // ---- state ----
    f2 h1p[5], h2p[5];
    #pragma unroll
    for (int k = 0; k < 5; ++k) { h1p[k] = mk2(0.f, 0.f); h2p[k] = mk2(0.f, 0.f); }
    float c1 = 0.0f, c2 = 0.0f;

    // ---- prologue: L0 at t=0 (h1 = 0 -> only x terms) ----
    {
        const f2 x0 = *reinterpret_cast<const f2*>(x + (size_t)b * 2);
        float z[4];
        #pragma unroll
        for (int g = 0; g < 4; ++g) {
            const f2 a = fma2(wi0p[g], x0, mk2(bb0[g], 0.f));
            z[g] = a.x + a.y;
        }
        const float di = 1.0f + fexp2(z[0]);
        const float df = 1.0f + fexp2(z[1]);
        const float dg = 1.0f + fexp2(z[2]);
        const float do_ = 1.0f + fexp2(z[3]);
        const float ipif = frcp(di * df);
        const float ipgo = frcp(dg * do_);
        const float ig = df * ipif;
        const float gg = fmaf(-2.0f, do_ * ipgo, 1.0f);
        const float og = dg * ipgo;
        c1 = ig * gg;                                    // c was 0
        const float dc = 1.0f + fexp2(LOG2E2 * c1);
        const float th = fmaf(-2.0f, frcp(dc), 1.0f);
        const float h1o = og * th;
        #pragma unroll
        for (int k = 0; k < 5; ++k)
            h1p[k] = mk2(bperm(hb[2 * k], h1o), bperm(hb[2 * k + 1], h1o));
    }

    f2 xv = *reinterpret_cast<const f2*>(x + ((size_t)1 * BATCH + b) * 2);

    // ---- main loop: iter t computes L0[t+1] and L1[t] ----
    for (int t = 0; t < SEQ - 1; ++t) {
        const int tn = (t + 2 < SEQ) ? (t + 2) : (SEQ - 1);
        const f2 xnext = *reinterpret_cast<const f2*>(x + ((size_t)tn * BATCH + b) * 2);

        // -- L0 dots for step t+1 (reads h1p = h1[t], xv = x[t+1]) --
        float z0[4];
        #pragma unroll
        for (int g = 0; g < 4; ++g) {
            f2 a = fma2(wi0p[g], xv, mk2(bb0[g], 0.f));
            #pragma unroll
            for (int k = 0; k < 5; ++k) a = fma2(wh0p[g][k], h1p[k], a);
            z0[g] = a.x + a.y;
        }
        // -- L0 activation --
        const float di0 = 1.0f + fexp2(z0[0]);
        const float df0 = 1.0f + fexp2(z0[1]);
        const float dg0 = 1.0f + fexp2(z0[2]);
        const float do0 = 1.0f + fexp2(z0[3]);
        const float ipif0 = frcp(di0 * df0);
        const float ipgo0 = frcp(dg0 * do0);
        const float i0 = df0 * ipif0;
        const float f0 = di0 * ipif0;
        const float g0 = fmaf(-2.0f, do0 * ipgo0, 1.0f);
        const float o0 = dg0 * ipgo0;
        c1 = fmaf(f0, c1, i0 * g0);
        const float dc0 = 1.0f + fexp2(LOG2E2 * c1);
        const float th0 = fmaf(-2.0f, frcp(dc0), 1.0f);
        const float h1o = o0 * th0;

        // issue h1[t+1] broadcast now; consumed next iteration (~70 instrs)
        f2 h1n[5];
        #pragma unroll
        for (int k = 0; k < 5; ++k)
            h1n[k] = mk2(bperm(hb[2 * k], h1o), bperm(hb[2 * k + 1], h1o));

        // -- L1 dots for step t (reads OLD h1p = h1[t], h2p = h2[t-1]) --
        float z1[4];
        #pragma unroll
        for (int g = 0; g < 4; ++g) {
            f2 a = fma2(wi1p[g][0], h1p[0], mk2(bb1[g], 0.f));
            #pragma unroll
            for (int k = 1; k < 5; ++k) a = fma2(wi1p[g][k], h1p[k], a);
            #pragma unroll
            for (int k = 0; k < 5; ++k) a = fma2(wh1p[g][k], h2p[k], a);
            z1[g] = a.x + a.y;
        }
        // -- L1 activation --
        const float di1 = 1.0f + fexp2(z1[0]);
        const float df1 = 1.0f + fexp2(z1[1]);
        const float dg1 = 1.0f + fexp2(z1[2]);
        const float do1 = 1.0f + fexp2(z1[3]);
        const float ipif1 = frcp(di1 * df1);
        const float ipgo1 = frcp(dg1 * do1);
        const float i1 = df1 * ipif1;
        const float f1 = di1 * ipif1;
        const float g1 = fmaf(-2.0f, do1 * ipgo1, 1.0f);
        const float o1 = dg1 * ipgo1;
        c2 = fmaf(f1, c2, i1 * g1);
        const float dc1 = 1.0f + fexp2(LOG2E2 * c2);
        const float th1 = fmaf(-2.0f, frcp(dc1), 1.0f);
        const float h2o = o1 * th1;

        // issue h2[t] broadcast; consumed next iteration in L1 dots
        #pragma unroll
        for (int k = 0; k < 5; ++k)
            h2p[k] = mk2(bperm(hb[2 * k], h2o), bperm(hb[2 * k + 1], h2o));

        // rotate pipeline registers
        #pragma unroll
        for (int k = 0; k < 5; ++k) h1p[k] = h1n[k];
        xv = xnext;
    }

    // ---- epilogue: L1 at t = SEQ-1 ----
    {
        float z1[4];
        #pragma unroll
        for (int g = 0; g < 4; ++g) {
            f2 a = fma2(wi1p[g][0], h1p[0], mk2(bb1[g], 0.f));
            #pragma unroll
            for (int k = 1; k < 5; ++k) a = fma2(wi1p[g][k], h1p[k], a);
            #pragma unroll
            for (int k = 0; k < 5; ++k) a = fma2(wh1p[g][k], h2p[k], a);
            z1[g] = a.x + a.y;
        }
        const float di1 = 1.0f + fexp2(z1[0]);
        const float df1 = 1.0f + fexp2(z1[1]);
        const float dg1 = 1.0f + fexp2(z1[2]);
        const float do1 = 1.0f + fexp2(z1[3]);
        const float ipif1 = frcp(di1 * df1);
        const float ipgo1 = frcp(dg1 * do1);
        const float i1 = df1 * ipif1;
        const float f1 = di1 * ipif1;
        const float g1 = fmaf(-2.0f, do1 * ipgo1, 1.0f);
        const float o1 = dg1 * ipgo1;
        c2 = fmaf(f1, c2, i1 * g1);
        const float dc1 = 1.0f + fexp2(LOG2E2 * c2);
        const float th1 = fmaf(-2.0f, frcp(dc1), 1.0f);
        const float h2o = o1 * th1;
        #pragma unroll
        for (int k = 0; k < 5; ++k)
            h2p[k] = mk2(bperm(hb[2 * k], h2o), bperm(hb[2 * k + 1], h2o));
    }

    // ---- FC: out[b][k] = fc_b[k] + sum_j fc_w[k][j] * h2[j] ----
    if (lane16 < 2) {
        float acc = fc_b[lane16];
        #pragma unroll
        for (int k = 0; k < 5; ++k) {
            acc = fmaf(fc_w[lane16 * HDIM + 2 * k],     h2p[k].x, acc);
            acc = fmaf(fc_w[lane16 * HDIM + 2 * k + 1], h2p[k].y, acc);
        }
        out[(size_t)b * 2 + lane16] = acc;
    }
}

extern "C" void kernel_launch(void* const* d_in, const int* in_sizes, int n_in,
                              void* d_out, int out_size, void* d_ws, size_t ws_size,
                              hipStream_t stream) {
    const float* x     = (const float*)d_in[0];
    const float* w_ih0 = (const float*)d_in[1];
    const float* w_hh0 = (const float*)d_in[2];
    const float* b_ih0 = (const float*)d_in[3];
    const float* b_hh0 = (const float*)d_in[4];
    const float* w_ih1 = (const float*)d_in[5];
    const float* w_hh1 = (const float*)d_in[6];
    const float* b_ih1 = (const float*)d_in[7];
    const float* b_hh1 = (const float*)d_in[8];
    const float* fc_w  = (const float*)d_in[9];
    const float* fc_b  = (const float*)d_in[10];
    float* out = (float*)d_out;

    const int threads = 256;                  // 16 batch elements per block
    const int blocks  = BATCH / 16;           // 512 blocks -> 2 blocks/CU
    lstm2_fc_kernel<<<blocks, threads, 0, stream>>>(
        x, w_ih0, w_hh0, b_ih0, b_hh0,
        w_ih1, w_hh1, b_ih1, b_hh1, fc_w, fc_b, out);
}